// Round 3
// baseline (111.645 us; speedup 1.0000x reference)
//
#include <hip/hip_runtime.h>
#include <stdint.h>

typedef __attribute__((ext_vector_type(4))) float  f32x4;
typedef __attribute__((ext_vector_type(8))) __bf16 bf16x8;

constexpr int F_DIM = 128;   // feature dim
constexpr int KC    = 256;   // number of centers
// u = max(sq, 1e-24)^(-1/(M-1)),  M = 1.7  ->  exponent on sq is -1/0.7
constexpr float ALPHA = -1.4285714285714286f;

__global__ __launch_bounds__(512, 2) void fcm_kernel(
        const float* __restrict__ x,
        const float* __restrict__ centers,
        float* __restrict__ out)
{
    // swizzled bf16 centers: row j, 16B chunk kc at byte j*256 + ((kc*16) ^ ((j&7)<<4))
    __shared__ __align__(16) unsigned char sB[KC * F_DIM * 2]; // 64 KiB
    __shared__ float sC2[KC];

    const int tid  = threadIdx.x;
    const int lane = tid & 63;
    const int wave = tid >> 6;

    // ---------- issue x loads FIRST so HBM stream overlaps center staging ----------
    const int rbase = blockIdx.x * 128 + wave * 16;
    const int lrow  = lane & 15;   // x-row within the wave's 16-row tile
    const int kq    = lane >> 4;   // k-quarter 0..3
    const float* xrow = x + (long long)(rbase + lrow) * F_DIM + kq * 8;

    f32x4 xa[4], xb[4];
    #pragma unroll
    for (int kb = 0; kb < 4; ++kb) {
        xa[kb] = *(const f32x4*)(xrow + kb * 32);
        xb[kb] = *(const f32x4*)(xrow + kb * 32 + 4);
    }

    // ---------- stage centers -> LDS (bf16, swizzled) + c2 (fp32 exact) ----------
    {
        const int j = tid >> 1;      // center index 0..255
        const int h = tid & 1;       // which half of the 128 features
        const float* src = centers + j * F_DIM + h * 64;
        float ss = 0.f;
        #pragma unroll
        for (int c = 0; c < 8; ++c) {
            f32x4 a = *(const f32x4*)(src + c * 8);
            f32x4 b = *(const f32x4*)(src + c * 8 + 4);
            ss += a.x*a.x + a.y*a.y + a.z*a.z + a.w*a.w;
            ss += b.x*b.x + b.y*b.y + b.z*b.z + b.w*b.w;
            union { __bf16 bh[8]; uint4 u4; } pk;
            pk.bh[0] = (__bf16)a.x; pk.bh[1] = (__bf16)a.y;
            pk.bh[2] = (__bf16)a.z; pk.bh[3] = (__bf16)a.w;
            pk.bh[4] = (__bf16)b.x; pk.bh[5] = (__bf16)b.y;
            pk.bh[6] = (__bf16)b.z; pk.bh[7] = (__bf16)b.w;
            const int kchunk = h * 8 + c;                       // 0..15
            const int off = j * 256 + ((kchunk * 16) ^ ((j & 7) << 4));
            *(uint4*)(sB + off) = pk.u4;
        }
        // pair-reduce the two half-row sums (lanes 2j, 2j+1 are adjacent)
        ss += __shfl_xor(ss, 1);
        if (h == 0) sC2[j] = ss;
    }
    __syncthreads();

    // ---------- convert x to bf16 fragments + exact fp32 x2 ----------
    bf16x8 fragX[4];
    float x2 = 0.f;
    #pragma unroll
    for (int kb = 0; kb < 4; ++kb) {
        f32x4 a = xa[kb], b = xb[kb];
        x2 += a.x*a.x + a.y*a.y + a.z*a.z + a.w*a.w;
        x2 += b.x*b.x + b.y*b.y + b.z*b.z + b.w*b.w;
        union { __bf16 bh[8]; bf16x8 v; } pk;
        pk.bh[0] = (__bf16)a.x; pk.bh[1] = (__bf16)a.y;
        pk.bh[2] = (__bf16)a.z; pk.bh[3] = (__bf16)a.w;
        pk.bh[4] = (__bf16)b.x; pk.bh[5] = (__bf16)b.y;
        pk.bh[6] = (__bf16)b.z; pk.bh[7] = (__bf16)b.w;
        fragX[kb] = pk.v;
    }
    // lanes {l, l^16, l^32, l^48} hold disjoint k-quarters of row (lane&15)
    x2 += __shfl_xor(x2, 16);
    x2 += __shfl_xor(x2, 32);
    // every lane now holds ||x_row||^2 for its row (lane&15)

    // ---------- MFMA: D[j_center][i_xrow], A = centers (LDS), B = x (regs) ----------
    // C/D layout: col = lane&15 -> x-row; row = kq*4 + r -> center within tile.
    f32x4 acc[16];
    #pragma unroll
    for (int nt = 0; nt < 16; ++nt) acc[nt] = f32x4{0.f, 0.f, 0.f, 0.f};

    const int sw = (lrow & 7) << 4;   // j = nt*16+lrow -> j&7 == lrow&7
    #pragma unroll
    for (int nt = 0; nt < 16; ++nt) {
        const unsigned char* brow = sB + nt * 4096 + lrow * 256;
        #pragma unroll
        for (int kb = 0; kb < 4; ++kb) {
            bf16x8 fc = *(const bf16x8*)(brow + ((kb * 64 + kq * 16) ^ sw));
            acc[nt] = __builtin_amdgcn_mfma_f32_16x16x32_bf16(fc, fragX[kb], acc[nt], 0, 0, 0);
        }
    }

    // ---------- epilogue: sq -> u = sq^ALPHA, row-normalize, dwordx4 store ----------
    // lane owns x-row (lane&15); its 64 u-values cover centers {nt*16 + kq*4 + r}
    float rowsum = 0.f;
    #pragma unroll
    for (int nt = 0; nt < 16; ++nt) {
        f32x4 c2v = *(const f32x4*)(sC2 + nt * 16 + kq * 4);
        #pragma unroll
        for (int r = 0; r < 4; ++r) {
            float sq = fmaxf(x2 + c2v[r] - 2.0f * acc[nt][r], 1e-24f);
            float u  = __builtin_amdgcn_exp2f(ALPHA * __builtin_amdgcn_logf(sq));
            acc[nt][r] = u;
            rowsum += u;
        }
    }
    // lanes l, l^16, l^32, l^48 hold disjoint center-subsets of the same x-row
    rowsum += __shfl_xor(rowsum, 16);
    rowsum += __shfl_xor(rowsum, 32);
    const float rinv = __builtin_amdgcn_rcpf(rowsum);

    float* orow = out + (long long)(rbase + lrow) * KC + kq * 4;
    #pragma unroll
    for (int nt = 0; nt < 16; ++nt) {
        f32x4 v = acc[nt] * rinv;
        *(f32x4*)(orow + nt * 16) = v;   // plain cached store: L2 merges 64B halves
    }
}

extern "C" void kernel_launch(void* const* d_in, const int* in_sizes, int n_in,
                              void* d_out, int out_size, void* d_ws, size_t ws_size,
                              hipStream_t stream) {
    const float* x       = (const float*)d_in[0];
    const float* centers = (const float*)d_in[1];
    float* out           = (float*)d_out;

    const int N      = in_sizes[0] / F_DIM;   // 262144
    const int blocks = N / 128;               // 128 rows per block
    fcm_kernel<<<blocks, 512, 0, stream>>>(x, centers, out);
}

// Round 4
// 103.982 us; speedup vs baseline: 1.0737x; 1.0737x over previous
//
#include <hip/hip_runtime.h>
#include <stdint.h>

typedef __attribute__((ext_vector_type(4))) float  f32x4;
typedef __attribute__((ext_vector_type(8))) __bf16 bf16x8;

constexpr int F_DIM = 128;   // feature dim
constexpr int KC    = 256;   // number of centers
// u = max(sq, 1e-24)^(-1/(M-1)),  M = 1.7  ->  exponent on sq is -1/0.7
constexpr float ALPHA = -1.4285714285714286f;

__global__ __launch_bounds__(512, 4) void fcm_kernel(
        const float* __restrict__ x,
        const float* __restrict__ centers,
        float* __restrict__ out)
{
    // swizzled bf16 centers: row j, 16B chunk kc at byte j*256 + ((kc*16) ^ ((j&7)<<4))
    __shared__ __align__(16) unsigned char sB[KC * F_DIM * 2]; // 64 KiB
    __shared__ float sC2[KC];

    const int tid  = threadIdx.x;
    const int lane = tid & 63;
    const int wave = tid >> 6;

    // ---------- stage centers -> LDS (bf16, swizzled) + c2 (fp32 exact) ----------
    {
        const int j = tid >> 1;      // center index 0..255
        const int h = tid & 1;       // which half of the 128 features
        const float* src = centers + j * F_DIM + h * 64;
        float ss = 0.f;
        #pragma unroll
        for (int c = 0; c < 8; ++c) {
            f32x4 a = *(const f32x4*)(src + c * 8);
            f32x4 b = *(const f32x4*)(src + c * 8 + 4);
            ss += a.x*a.x + a.y*a.y + a.z*a.z + a.w*a.w;
            ss += b.x*b.x + b.y*b.y + b.z*b.z + b.w*b.w;
            union { __bf16 bh[8]; uint4 u4; } pk;
            pk.bh[0] = (__bf16)a.x; pk.bh[1] = (__bf16)a.y;
            pk.bh[2] = (__bf16)a.z; pk.bh[3] = (__bf16)a.w;
            pk.bh[4] = (__bf16)b.x; pk.bh[5] = (__bf16)b.y;
            pk.bh[6] = (__bf16)b.z; pk.bh[7] = (__bf16)b.w;
            const int kchunk = h * 8 + c;                       // 0..15
            const int off = j * 256 + ((kchunk * 16) ^ ((j & 7) << 4));
            *(uint4*)(sB + off) = pk.u4;
        }
        // pair-reduce the two half-row sums (lanes 2j, 2j+1 are adjacent)
        ss += __shfl_xor(ss, 1);
        if (h == 0) sC2[j] = ss;
    }
    __syncthreads();

    // ---------- load x fragments (16 rows per wave) + exact fp32 x2 ----------
    const int rbase = blockIdx.x * 128 + wave * 16;
    const int lrow  = lane & 15;   // x-row within the wave's 16-row tile
    const int kq    = lane >> 4;   // k-quarter 0..3
    const float* xrow = x + (long long)(rbase + lrow) * F_DIM + kq * 8;

    bf16x8 fragX[4];
    float x2 = 0.f;
    #pragma unroll
    for (int kb = 0; kb < 4; ++kb) {
        f32x4 a = *(const f32x4*)(xrow + kb * 32);
        f32x4 b = *(const f32x4*)(xrow + kb * 32 + 4);
        x2 += a.x*a.x + a.y*a.y + a.z*a.z + a.w*a.w;
        x2 += b.x*b.x + b.y*b.y + b.z*b.z + b.w*b.w;
        union { __bf16 bh[8]; bf16x8 v; } pk;
        pk.bh[0] = (__bf16)a.x; pk.bh[1] = (__bf16)a.y;
        pk.bh[2] = (__bf16)a.z; pk.bh[3] = (__bf16)a.w;
        pk.bh[4] = (__bf16)b.x; pk.bh[5] = (__bf16)b.y;
        pk.bh[6] = (__bf16)b.z; pk.bh[7] = (__bf16)b.w;
        fragX[kb] = pk.v;
    }
    // lanes {l, l^16, l^32, l^48} hold disjoint k-quarters of row (lane&15)
    x2 += __shfl_xor(x2, 16);
    x2 += __shfl_xor(x2, 32);
    // every lane now holds ||x_row||^2 for its row (lane&15)

    // ---------- MFMA: D[j_center][i_xrow], A = centers (LDS), B = x (regs) ----------
    // C/D layout: col = lane&15 -> x-row; row = kq*4 + r -> center within tile.
    f32x4 acc[16];
    #pragma unroll
    for (int nt = 0; nt < 16; ++nt) acc[nt] = f32x4{0.f, 0.f, 0.f, 0.f};

    const int sw = (lrow & 7) << 4;   // j = nt*16+lrow -> j&7 == lrow&7
    #pragma unroll
    for (int nt = 0; nt < 16; ++nt) {
        const unsigned char* brow = sB + nt * 4096 + lrow * 256;
        #pragma unroll
        for (int kb = 0; kb < 4; ++kb) {
            bf16x8 fc = *(const bf16x8*)(brow + ((kb * 64 + kq * 16) ^ sw));
            acc[nt] = __builtin_amdgcn_mfma_f32_16x16x32_bf16(fc, fragX[kb], acc[nt], 0, 0, 0);
        }
    }

    // ---------- epilogue: sq -> u = sq^ALPHA, row-normalize, dwordx4 store ----------
    // lane owns x-row (lane&15); its 64 u-values cover centers {nt*16 + kq*4 + r}
    float rowsum = 0.f;
    #pragma unroll
    for (int nt = 0; nt < 16; ++nt) {
        f32x4 c2v = *(const f32x4*)(sC2 + nt * 16 + kq * 4);
        #pragma unroll
        for (int r = 0; r < 4; ++r) {
            float sq = fmaxf(x2 + c2v[r] - 2.0f * acc[nt][r], 1e-24f);
            float u  = __builtin_amdgcn_exp2f(ALPHA * __builtin_amdgcn_logf(sq));
            acc[nt][r] = u;
            rowsum += u;
        }
    }
    // lanes l, l^16, l^32, l^48 hold disjoint center-subsets of the same x-row
    rowsum += __shfl_xor(rowsum, 16);
    rowsum += __shfl_xor(rowsum, 32);
    const float rinv = __builtin_amdgcn_rcpf(rowsum);

    float* orow = out + (long long)(rbase + lrow) * KC + kq * 4;
    #pragma unroll
    for (int nt = 0; nt < 16; ++nt) {
        f32x4 v = acc[nt] * rinv;
        *(f32x4*)(orow + nt * 16) = v;   // plain cached store: L2 merges 64B halves
    }
}

extern "C" void kernel_launch(void* const* d_in, const int* in_sizes, int n_in,
                              void* d_out, int out_size, void* d_ws, size_t ws_size,
                              hipStream_t stream) {
    const float* x       = (const float*)d_in[0];
    const float* centers = (const float*)d_in[1];
    float* out           = (float*)d_out;

    const int N      = in_sizes[0] / F_DIM;   // 262144
    const int blocks = N / 128;               // 128 rows per block
    fcm_kernel<<<blocks, 512, 0, stream>>>(x, centers, out);
}